// Round 17
// baseline (45.491 us; speedup 1.0000x reference)
//
#include <hip/hip_runtime.h>
#include <hip/hip_bf16.h>

typedef __attribute__((ext_vector_type(8))) __bf16 bf16x8;
typedef __attribute__((ext_vector_type(4))) float f32x4;

namespace {

constexpr int L = 2048;      // query length (== S)
constexpr int E = 64;        // embed dim == value dim
constexpr int NHEAD = 16;    // B*H reinterpreted heads
constexpr float SCALE = 0.125f;   // 1/sqrt(64)
constexpr float LOG2E = 1.44269504f;
constexpr float TWO_LOG2E = 2.88539008f;

// workspace layout (bytes)
constexpr size_t KN_OFF = 4096;                               // f32 [16][2048]  (-log2e*|k|^2)
constexpr size_t KB_OFF = KN_OFF + (size_t)NHEAD * L * 4;     // bf16 [16][2048][64]
constexpr size_t VT_OFF = KB_OFF + (size_t)NHEAD * L * E * 2; // bf16 [16][64][2048]

// XOR swizzle within a 128-byte LDS row (verified low-conflict rounds 5-16)
__device__ __forceinline__ int swz(int row, int byte_in_row) {
  const int f = (row & 3) | (((row >> 3) & 1) << 2);
  return row * 128 + (byte_in_row ^ (f << 4));
}

__device__ __forceinline__ unsigned pack_bf16(float a, float b) {
  union { __bf16 h[2]; unsigned u; } p;
  p.h[0] = (__bf16)a; p.h[1] = (__bf16)b;
  return p.u;
}

__device__ __forceinline__ void cvt_row16(const float4* src, float& pn,
                                          bf16x8& w0, bf16x8& w1) {
  float4 a = src[0], c = src[1];
  pn += a.x*a.x + a.y*a.y + a.z*a.z + a.w*a.w;
  pn += c.x*c.x + c.y*c.y + c.z*c.z + c.w*c.w;
  w0[0]=(__bf16)a.x; w0[1]=(__bf16)a.y; w0[2]=(__bf16)a.z; w0[3]=(__bf16)a.w;
  w0[4]=(__bf16)c.x; w0[5]=(__bf16)c.y; w0[6]=(__bf16)c.z; w0[7]=(__bf16)c.w;
  float4 d = src[2], e = src[3];
  pn += d.x*d.x + d.y*d.y + d.z*d.z + d.w*d.w;
  pn += e.x*e.x + e.y*e.y + e.z*e.z + e.w*e.w;
  w1[0]=(__bf16)d.x; w1[1]=(__bf16)d.y; w1[2]=(__bf16)d.z; w1[3]=(__bf16)d.w;
  w1[4]=(__bf16)e.x; w1[5]=(__bf16)e.y; w1[6]=(__bf16)e.z; w1[7]=(__bf16)e.w;
}

// merged prep: blocks [0,512) convert K -> bf16 + scaled norms; [512,1024) transpose V
__global__ __launch_bounds__(256)
void prep(const float* __restrict__ Kg, const float* __restrict__ Vg,
          __bf16* __restrict__ Kb, float* __restrict__ kn,
          __bf16* __restrict__ Vt) {
  __shared__ float Vs[64][65];
  const int t = threadIdx.x;
  if (blockIdx.x < 512) {
    const int row = blockIdx.x * 64 + (t >> 2);
    const int seg = t & 3;
    const float4* src = reinterpret_cast<const float4*>(
        Kg + (size_t)row * E + seg * 16);
    float pn = 0.f; bf16x8 w0, w1;
    cvt_row16(src, pn, w0, w1);
    __bf16* dst = Kb + (size_t)row * E + seg * 16;
    *reinterpret_cast<bf16x8*>(dst)     = w0;
    *reinterpret_cast<bf16x8*>(dst + 8) = w1;
    pn += __shfl_xor(pn, 1);
    pn += __shfl_xor(pn, 2);
    if (seg == 0) kn[row] = -LOG2E * pn;      // pre-scaled
  } else {
    const int bb = blockIdx.x - 512;
    const int n  = bb >> 5;    // head 0..15
    const int st = bb & 31;    // s-tile of 64
    const int b = n >> 3, h = n & 7;
    {
      const int srow = t >> 2, seg = t & 3;
      const float4* src = reinterpret_cast<const float4*>(
          Vg + ((size_t)b * L + st * 64 + srow) * 512 + h * 64 + seg * 16);
      #pragma unroll
      for (int jj = 0; jj < 4; ++jj) {
        float4 a = src[jj];
        Vs[srow][seg*16 + jj*4 + 0] = a.x;
        Vs[srow][seg*16 + jj*4 + 1] = a.y;
        Vs[srow][seg*16 + jj*4 + 2] = a.z;
        Vs[srow][seg*16 + jj*4 + 3] = a.w;
      }
    }
    __syncthreads();
    {
      const int d = t >> 2, sg = t & 3;
      bf16x8 o0, o1;
      #pragma unroll
      for (int i = 0; i < 8; ++i) o0[i] = (__bf16)Vs[sg*16 + i][d];
      #pragma unroll
      for (int i = 0; i < 8; ++i) o1[i] = (__bf16)Vs[sg*16 + 8 + i][d];
      __bf16* dst = Vt + (size_t)n * (E * L) + (size_t)d * L + st * 64 + sg * 16;
      *reinterpret_cast<bf16x8*>(dst)     = o0;
      *reinterpret_cast<bf16x8*>(dst + 8) = o1;
    }
  }
}

// ---- main attention: 8 waves = 2 groups (even/odd s-chunks), LDS combine.
// Single-buffered staging (32KB total) -> 4 blocks/CU resident (32 waves/CU).
// Co-resident pair (id, id+256) balance: lt = (u<16)? u : 47-u (pair sum 31).
__global__ __launch_bounds__(512, 4)
void degr_attn(const float* __restrict__ Qg, const __bf16* __restrict__ Kb,
               const __bf16* __restrict__ Vt, const float* __restrict__ kng,
               float* __restrict__ Og) {
  __shared__ char smem[32768];
  // staging: group g: K @ g*16384 (8KB), V @ g*16384+8192 (8KB)
  // epilogue overlay: Cbuf 64x65 f32 @0, Dbuf 64 f32 @17408

  const int id = blockIdx.x;
  const int n  = (id & 7) | (((id >> 3) & 1) << 3);  // 2 heads per XCD
  const int u  = id >> 4;                            // 0..31
  const int lt = (u < 16) ? u : 47 - u;              // pair (u, 31-u) per CU
  const int l0 = lt * 64;
  const int b = n >> 3, h = n & 7;

  const int t = threadIdx.x;
  const int wave = t >> 6, grp = wave >> 2, w4 = wave & 3;
  const int lane = t & 63, lg = lane >> 4, lr = lane & 15;
  const int gt = t & 255;   // group-local thread

  char* kbase = smem + grp * 16384;
  char* vbase = kbase + 8192;
  float*  Cbuf = (float*)smem;                 // 64*65 f32 (overlay)
  float*  Dbuf = (float*)(smem + 17408);       // 64 f32

  const float*  Qh  = Qg  + (size_t)n * (L * E);
  const __bf16* Kh  = Kb  + (size_t)n * (L * E);
  const __bf16* Vh  = Vt  + (size_t)n * (E * L);
  const float*  knh = kng + (size_t)n * L;

  // ---- Q fragments direct from global (f32 -> bf16 in regs) + lane-local qn ----
  const int l_glob = l0 + 16 * w4 + lr;
  bf16x8 qf0, qf1;
  float qnL;
  {
    const float* qp = Qh + (size_t)l_glob * E + 8 * lg;
    float4 a = *reinterpret_cast<const float4*>(qp);
    float4 d = *reinterpret_cast<const float4*>(qp + 4);
    float4 a2 = *reinterpret_cast<const float4*>(qp + 32);
    float4 d2v = *reinterpret_cast<const float4*>(qp + 36);
    float pn = 0.f;
    #pragma unroll
    for (int i = 0; i < 4; ++i) {
      float v0 = (i==0)?a.x:(i==1)?a.y:(i==2)?a.z:a.w;
      float v1 = (i==0)?d.x:(i==1)?d.y:(i==2)?d.z:d.w;
      float v2 = (i==0)?a2.x:(i==1)?a2.y:(i==2)?a2.z:a2.w;
      float v3 = (i==0)?d2v.x:(i==1)?d2v.y:(i==2)?d2v.z:d2v.w;
      qf0[i]   = (__bf16)v0;  qf0[i+4] = (__bf16)v1;
      qf1[i]   = (__bf16)v2;  qf1[i+4] = (__bf16)v3;
      float f;
      f = (float)qf0[i];   pn += f*f;
      f = (float)qf0[i+4]; pn += f*f;
      f = (float)qf1[i];   pn += f*f;
      f = (float)qf1[i+4]; pn += f*f;
    }
    pn += __shfl_xor(pn, 16);
    pn += __shfl_xor(pn, 32);
    qnL = -LOG2E * pn;       // pre-scaled |q|^2
  }

  // ---- precomputed LDS offsets (all addressing hoisted out of the loop) ----
  const int srow = gt >> 2;
  const int scol = (gt & 3) * 2;
  const int wk0 = swz(srow, scol*16);
  const int wk1 = swz(srow, scol*16 + 16);
  int koffL[4], koffH[4];
  #pragma unroll
  for (int hx = 0; hx < 4; ++hx) {
    const int krow = 32*(hx>>1) + 8*(lr>>2) + 4*(hx&1) + (lr&3);
    koffL[hx] = swz(krow, lg*16);
    koffH[hx] = swz(krow, 64 + lg*16);
  }
  int voff[2][4];
  #pragma unroll
  for (int sc = 0; sc < 2; ++sc)
    #pragma unroll
    for (int dsb = 0; dsb < 4; ++dsb)
      voff[sc][dsb] = swz(dsb*16 + lr, sc*64 + lg*16);

  bf16x8 kr0, kr1, vr0, vr1;
  auto loadKV = [&](int c) {
    const int s0 = c * 64;
    const __bf16* kp = Kh + (size_t)(s0 + srow) * E + scol * 8;
    kr0 = *reinterpret_cast<const bf16x8*>(kp);
    kr1 = *reinterpret_cast<const bf16x8*>(kp + 8);
    const __bf16* vp = Vh + (size_t)srow * L + s0 + scol * 8;
    vr0 = *reinterpret_cast<const bf16x8*>(vp);
    vr1 = *reinterpret_cast<const bf16x8*>(vp + 8);
  };
  auto writeKV = [&]() {
    *reinterpret_cast<bf16x8*>(kbase + wk0) = kr0;
    *reinterpret_cast<bf16x8*>(kbase + wk1) = kr1;
    *reinterpret_cast<bf16x8*>(vbase + wk0) = vr0;
    *reinterpret_cast<bf16x8*>(vbase + wk1) = vr1;
  };

  f32x4 oacc[4];
  #pragma unroll
  for (int i = 0; i < 4; ++i) oacc[i] = (f32x4){0.f, 0.f, 0.f, 0.f};
  float den = 0.f;

  auto compute = [&](int c, bool MASK) {
    const int s_base = c * 64;
    // prefetch kn for all 4 subtiles (consumed after QK^T)
    float4 kn4[4];
    kn4[0] = *reinterpret_cast<const float4*>(knh + s_base + 8*lg);
    kn4[1] = *reinterpret_cast<const float4*>(knh + s_base + 8*lg + 4);
    kn4[2] = *reinterpret_cast<const float4*>(knh + s_base + 32 + 8*lg);
    kn4[3] = *reinterpret_cast<const float4*>(knh + s_base + 36 + 8*lg);

    __builtin_amdgcn_s_setprio(1);
    unsigned up[4][2];
    #pragma unroll
    for (int hx = 0; hx < 4; ++hx) {
      const bf16x8 kf0 = *reinterpret_cast<const bf16x8*>(kbase + koffL[hx]);
      const bf16x8 kf1 = *reinterpret_cast<const bf16x8*>(kbase + koffH[hx]);
      f32x4 acc = (f32x4){0.f, 0.f, 0.f, 0.f};
      acc = __builtin_amdgcn_mfma_f32_16x16x32_bf16(kf0, qf0, acc, 0, 0, 0);
      acc = __builtin_amdgcn_mfma_f32_16x16x32_bf16(kf1, qf1, acc, 0, 0, 0);
      float w[4];
      #pragma unroll
      for (int r = 0; r < 4; ++r) {
        const float knv = (r==0)?kn4[hx].x:(r==1)?kn4[hx].y:(r==2)?kn4[hx].z:kn4[hx].w;
        // arg = -log2e * d2  (clamped to <= 0); raw v_exp_f32 underflows to 0
        float arg = fminf(fmaf(TWO_LOG2E, acc[r], qnL + knv), 0.f);
        float e1  = __builtin_amdgcn_exp2f(arg);    // e^{-d2}
        float y   = fmaf(-SCALE, e1, SCALE);        // in [0, 0.125]
        float tt  = fmaf(0.5f, y, 1.0f);
        float wv  = fmaf(y, tt, 1.0f);              // exp(y), poly, err<3.4e-4
        if (MASK) {
          const int sof = 32*(hx>>1) + 8*lg + 4*(hx&1);
          wv = (s_base + sof + r <= l_glob) ? wv : 0.f;
        }
        den += wv;
        w[r] = wv;
      }
      up[hx][0] = pack_bf16(w[0], w[1]);
      up[hx][1] = pack_bf16(w[2], w[3]);
    }
    // ---- PV: P fragment lane-local by sigma construction ----
    #pragma unroll
    for (int sc = 0; sc < 2; ++sc) {
      union { unsigned u[4]; bf16x8 v; } pb;
      pb.u[0] = up[2*sc][0];
      pb.u[1] = up[2*sc][1];
      pb.u[2] = up[2*sc+1][0];
      pb.u[3] = up[2*sc+1][1];
      const bf16x8 pf = pb.v;
      #pragma unroll
      for (int dsb = 0; dsb < 4; ++dsb) {
        const bf16x8 vf = *reinterpret_cast<const bf16x8*>(vbase + voff[sc][dsb]);
        oacc[dsb] = __builtin_amdgcn_mfma_f32_16x16x32_bf16(pf, vf, oacc[dsb], 0, 0, 0);
      }
    }
    __builtin_amdgcn_s_setprio(0);
  };

  // ---- chunk loop: single-buffered, reg-carried prefetch ----
  const int n_it = (lt >> 1) + 1;
  loadKV(grp <= lt ? grp : lt);
  writeKV();
  __syncthreads();
  for (int i = 0; i < n_it; ++i) {
    const int c = 2 * i + grp;
    const bool more = (i + 1 < n_it);
    if (more) {
      int cn = 2 * (i + 1) + grp;
      loadKV(cn <= lt ? cn : lt);          // prefetch to regs (in flight)
    }
    if (c <= lt) compute(c, c == lt);      // grp-1 pad chunk skipped
    __syncthreads();                       // group-mates done reading
    if (more) {
      writeKV();
      __syncthreads();                     // staged data visible
    }
  }

  // ---- den: reduce over lg (per l = lr) ----
  den += __shfl_xor(den, 16);
  den += __shfl_xor(den, 32);

  // ---- combine groups through LDS ----
  if (grp == 1) {
    #pragma unroll
    for (int dsb = 0; dsb < 4; ++dsb)
      #pragma unroll
      for (int r = 0; r < 4; ++r)
        Cbuf[(16*w4 + 4*lg + r) * 65 + 16*dsb + lr] = oacc[dsb][r];
    if (lane < 16) Dbuf[16*w4 + lr] = den;
  }
  __syncthreads();
  if (grp == 0) {
    const float dtot = den + Dbuf[16*w4 + lr];   // total den for l = 16*w4+lr
    float inv[4];
    #pragma unroll
    for (int r = 0; r < 4; ++r)
      inv[r] = 1.0f / __shfl(dtot, 4*lg + r);
    float* obase = Og + ((size_t)b * L + l0 + 16*w4) * 512 + h * 64;
    #pragma unroll
    for (int r = 0; r < 4; ++r) {
      float* orow = obase + (size_t)(4*lg + r) * 512;
      #pragma unroll
      for (int dsb = 0; dsb < 4; ++dsb) {
        const float s = oacc[dsb][r] + Cbuf[(16*w4 + 4*lg + r) * 65 + 16*dsb + lr];
        orow[16*dsb + lr] = s * inv[r];
      }
    }
  }
}

} // namespace

extern "C" void kernel_launch(void* const* d_in, const int* in_sizes, int n_in,
                              void* d_out, int out_size, void* d_ws, size_t ws_size,
                              hipStream_t stream) {
  (void)in_sizes; (void)n_in; (void)out_size; (void)ws_size;
  const float* q = (const float*)d_in[0];
  const float* k = (const float*)d_in[1];
  const float* v = (const float*)d_in[2];
  float*       o = (float*)d_out;

  char* ws = (char*)d_ws;
  float*  kn = (float*)(ws + KN_OFF);
  __bf16* Kb = (__bf16*)(ws + KB_OFF);
  __bf16* Vt = (__bf16*)(ws + VT_OFF);

  prep<<<dim3(1024), dim3(256), 0, stream>>>(k, v, Kb, kn, Vt);
  degr_attn<<<dim3(512), dim3(512), 0, stream>>>(q, Kb, Vt, kn, o);
}

// Round 18
// 38.965 us; speedup vs baseline: 1.1675x; 1.1675x over previous
//
#include <hip/hip_runtime.h>
#include <hip/hip_bf16.h>

typedef __attribute__((ext_vector_type(8))) __bf16 bf16x8;
typedef __attribute__((ext_vector_type(4))) float f32x4;

namespace {

constexpr int L = 2048;      // query length (== S)
constexpr int E = 64;        // embed dim == value dim
constexpr int NHEAD = 16;    // B*H reinterpreted heads
constexpr float LOG2E = 1.44269504f;
constexpr float TWO_LOG2E = 2.88539008f;

// workspace layout (bytes)
constexpr size_t KN_OFF = 4096;                               // f32 [16][2048]  (-log2e*|k|^2 - 3)
constexpr size_t KB_OFF = KN_OFF + (size_t)NHEAD * L * 4;     // bf16 [16][2048][64]
constexpr size_t VT_OFF = KB_OFF + (size_t)NHEAD * L * E * 2; // bf16 [16][64][2048]

// XOR swizzle within a 128-byte LDS row (verified low-conflict rounds 5-16)
__device__ __forceinline__ int swz(int row, int byte_in_row) {
  const int f = (row & 3) | (((row >> 3) & 1) << 2);
  return row * 128 + (byte_in_row ^ (f << 4));
}

__device__ __forceinline__ unsigned pack_bf16(float a, float b) {
  union { __bf16 h[2]; unsigned u; } p;
  p.h[0] = (__bf16)a; p.h[1] = (__bf16)b;
  return p.u;
}

__device__ __forceinline__ void cvt_row16(const float4* src, float& pn,
                                          bf16x8& w0, bf16x8& w1) {
  float4 a = src[0], c = src[1];
  pn += a.x*a.x + a.y*a.y + a.z*a.z + a.w*a.w;
  pn += c.x*c.x + c.y*c.y + c.z*c.z + c.w*c.w;
  w0[0]=(__bf16)a.x; w0[1]=(__bf16)a.y; w0[2]=(__bf16)a.z; w0[3]=(__bf16)a.w;
  w0[4]=(__bf16)c.x; w0[5]=(__bf16)c.y; w0[6]=(__bf16)c.z; w0[7]=(__bf16)c.w;
  float4 d = src[2], e = src[3];
  pn += d.x*d.x + d.y*d.y + d.z*d.z + d.w*d.w;
  pn += e.x*e.x + e.y*e.y + e.z*e.z + e.w*e.w;
  w1[0]=(__bf16)d.x; w1[1]=(__bf16)d.y; w1[2]=(__bf16)d.z; w1[3]=(__bf16)d.w;
  w1[4]=(__bf16)e.x; w1[5]=(__bf16)e.y; w1[6]=(__bf16)e.z; w1[7]=(__bf16)e.w;
}

// merged prep: blocks [0,512) convert K -> bf16 + biased scaled norms;
// [512,1024) transpose V.  kn stores (-log2e*|k|^2 - 3): the -3 folds the
// SCALE=2^-3 factor into the exp2 argument (u = SCALE*e^{-d2} = 2^{arg-3}).
__global__ __launch_bounds__(256)
void prep(const float* __restrict__ Kg, const float* __restrict__ Vg,
          __bf16* __restrict__ Kb, float* __restrict__ kn,
          __bf16* __restrict__ Vt) {
  __shared__ float Vs[64][65];
  const int t = threadIdx.x;
  if (blockIdx.x < 512) {
    const int row = blockIdx.x * 64 + (t >> 2);
    const int seg = t & 3;
    const float4* src = reinterpret_cast<const float4*>(
        Kg + (size_t)row * E + seg * 16);
    float pn = 0.f; bf16x8 w0, w1;
    cvt_row16(src, pn, w0, w1);
    __bf16* dst = Kb + (size_t)row * E + seg * 16;
    *reinterpret_cast<bf16x8*>(dst)     = w0;
    *reinterpret_cast<bf16x8*>(dst + 8) = w1;
    pn += __shfl_xor(pn, 1);
    pn += __shfl_xor(pn, 2);
    if (seg == 0) kn[row] = fmaf(-LOG2E, pn, -3.0f);   // pre-scaled + bias
  } else {
    const int bb = blockIdx.x - 512;
    const int n  = bb >> 5;    // head 0..15
    const int st = bb & 31;    // s-tile of 64
    const int b = n >> 3, h = n & 7;
    {
      const int srow = t >> 2, seg = t & 3;
      const float4* src = reinterpret_cast<const float4*>(
          Vg + ((size_t)b * L + st * 64 + srow) * 512 + h * 64 + seg * 16);
      #pragma unroll
      for (int jj = 0; jj < 4; ++jj) {
        float4 a = src[jj];
        Vs[srow][seg*16 + jj*4 + 0] = a.x;
        Vs[srow][seg*16 + jj*4 + 1] = a.y;
        Vs[srow][seg*16 + jj*4 + 2] = a.z;
        Vs[srow][seg*16 + jj*4 + 3] = a.w;
      }
    }
    __syncthreads();
    {
      const int d = t >> 2, sg = t & 3;
      bf16x8 o0, o1;
      #pragma unroll
      for (int i = 0; i < 8; ++i) o0[i] = (__bf16)Vs[sg*16 + i][d];
      #pragma unroll
      for (int i = 0; i < 8; ++i) o1[i] = (__bf16)Vs[sg*16 + 8 + i][d];
      __bf16* dst = Vt + (size_t)n * (E * L) + (size_t)d * L + st * 64 + sg * 16;
      *reinterpret_cast<bf16x8*>(dst)     = o0;
      *reinterpret_cast<bf16x8*>(dst + 8) = o1;
    }
  }
}

// ---- main attention: 8 waves = 2 groups (even/odd s-chunks), LDS combine ----
// Score path uses softmax constant-factor cancellation:
//   w' = w / e^SCALE = exp(-SCALE*e^{-d2}) ~= 1 - u + u^2/2,  u = 2^{arg-3}
// (the 1/e^SCALE factor cancels in O = sum(w V)/sum(w)).
__global__ __launch_bounds__(512, 4)
void degr_attn(const float* __restrict__ Qg, const __bf16* __restrict__ Kb,
               const __bf16* __restrict__ Vt, const float* __restrict__ kng,
               float* __restrict__ Og) {
  __shared__ char smem[65536];
  // per-group staging: K dbuf 16KB + V dbuf 16KB; overlay: Cbuf/Dbuf

  const int id = blockIdx.x;
  const int n  = (id & 7) | (((id >> 3) & 1) << 3);  // 2 heads per XCD
  const int u  = id >> 4;                            // 0..31
  const int lt = 31 - u;                             // LPT order (harmless)
  const int l0 = lt * 64;
  const int b = n >> 3, h = n & 7;

  const int t = threadIdx.x;
  const int wave = t >> 6, grp = wave >> 2, w4 = wave & 3;
  const int lane = t & 63, lg = lane >> 4, lr = lane & 15;
  const int gt = t & 255;   // group-local thread

  char* kbase = smem + grp * 32768;            // K: [2][8192] bytes
  char* vbase = smem + grp * 32768 + 16384;    // V: [2][8192] bytes
  float*  Cbuf = (float*)smem;                 // 64*65 f32 (overlay)
  float*  Dbuf = (float*)(smem + 17408);       // 64 f32

  const float*  Qh  = Qg  + (size_t)n * (L * E);
  const __bf16* Kh  = Kb  + (size_t)n * (L * E);
  const __bf16* Vh  = Vt  + (size_t)n * (E * L);
  const float*  knh = kng + (size_t)n * L;

  // ---- Q fragments direct from global (f32 -> bf16 in regs) + lane-local qn ----
  const int l_glob = l0 + 16 * w4 + lr;
  bf16x8 qf0, qf1;
  float qnL;
  {
    const float* qp = Qh + (size_t)l_glob * E + 8 * lg;
    float4 a = *reinterpret_cast<const float4*>(qp);
    float4 d = *reinterpret_cast<const float4*>(qp + 4);
    float4 a2 = *reinterpret_cast<const float4*>(qp + 32);
    float4 d2v = *reinterpret_cast<const float4*>(qp + 36);
    float pn = 0.f;
    #pragma unroll
    for (int i = 0; i < 4; ++i) {
      float v0 = (i==0)?a.x:(i==1)?a.y:(i==2)?a.z:a.w;
      float v1 = (i==0)?d.x:(i==1)?d.y:(i==2)?d.z:d.w;
      float v2 = (i==0)?a2.x:(i==1)?a2.y:(i==2)?a2.z:a2.w;
      float v3 = (i==0)?d2v.x:(i==1)?d2v.y:(i==2)?d2v.z:d2v.w;
      qf0[i]   = (__bf16)v0;  qf0[i+4] = (__bf16)v1;
      qf1[i]   = (__bf16)v2;  qf1[i+4] = (__bf16)v3;
      float f;
      f = (float)qf0[i];   pn += f*f;
      f = (float)qf0[i+4]; pn += f*f;
      f = (float)qf1[i];   pn += f*f;
      f = (float)qf1[i+4]; pn += f*f;
    }
    pn += __shfl_xor(pn, 16);
    pn += __shfl_xor(pn, 32);
    qnL = -LOG2E * pn;       // pre-scaled |q|^2 (bias lives in kn)
  }

  // ---- precomputed LDS offsets (all addressing hoisted out of the loop) ----
  const int srow = gt >> 2;
  const int scol = (gt & 3) * 2;
  const int wk0 = swz(srow, scol*16);
  const int wk1 = swz(srow, scol*16 + 16);
  int koffL[4], koffH[4];
  #pragma unroll
  for (int hx = 0; hx < 4; ++hx) {
    const int krow = 32*(hx>>1) + 8*(lr>>2) + 4*(hx&1) + (lr&3);
    koffL[hx] = swz(krow, lg*16);
    koffH[hx] = swz(krow, 64 + lg*16);
  }
  int voff[2][4];
  #pragma unroll
  for (int sc = 0; sc < 2; ++sc)
    #pragma unroll
    for (int dsb = 0; dsb < 4; ++dsb)
      voff[sc][dsb] = swz(dsb*16 + lr, sc*64 + lg*16);

  bf16x8 kr0, kr1, vr0, vr1;
  auto loadKV = [&](int c) {
    const int s0 = c * 64;
    const __bf16* kp = Kh + (size_t)(s0 + srow) * E + scol * 8;
    kr0 = *reinterpret_cast<const bf16x8*>(kp);
    kr1 = *reinterpret_cast<const bf16x8*>(kp + 8);
    const __bf16* vp = Vh + (size_t)srow * L + s0 + scol * 8;
    vr0 = *reinterpret_cast<const bf16x8*>(vp);
    vr1 = *reinterpret_cast<const bf16x8*>(vp + 8);
  };
  auto writeKV = [&](int WB) {       // WB: literal byte offset 0 / 8192
    *reinterpret_cast<bf16x8*>(kbase + WB + wk0) = kr0;
    *reinterpret_cast<bf16x8*>(kbase + WB + wk1) = kr1;
    *reinterpret_cast<bf16x8*>(vbase + WB + wk0) = vr0;
    *reinterpret_cast<bf16x8*>(vbase + WB + wk1) = vr1;
  };

  const int n_it = (lt >> 1) + 1;
  loadKV(grp <= lt ? grp : lt);
  writeKV(0);
  __syncthreads();

  f32x4 oacc[4];
  #pragma unroll
  for (int i = 0; i < 4; ++i) oacc[i] = (f32x4){0.f, 0.f, 0.f, 0.f};
  float den = 0.f;

  auto body = [&](int i, const int B, const bool MASK) {
    const int c = 2 * i + grp;
    const bool more = (i + 1 < n_it);
    if (more) {
      int cn = 2 * (i + 1) + grp;
      loadKV(cn <= lt ? cn : lt);
    }
    const int s_base = c * 64;
    const char* kb = kbase + B;
    const char* vb = vbase + B;

    // prefetch kn for all 4 subtiles (consumed after QK^T)
    float4 kn4[4];
    kn4[0] = *reinterpret_cast<const float4*>(knh + s_base + 8*lg);
    kn4[1] = *reinterpret_cast<const float4*>(knh + s_base + 8*lg + 4);
    kn4[2] = *reinterpret_cast<const float4*>(knh + s_base + 32 + 8*lg);
    kn4[3] = *reinterpret_cast<const float4*>(knh + s_base + 36 + 8*lg);

    __builtin_amdgcn_s_setprio(1);
    unsigned up[4][2];
    #pragma unroll
    for (int hx = 0; hx < 4; ++hx) {
      const bf16x8 kf0 = *reinterpret_cast<const bf16x8*>(kb + koffL[hx]);
      const bf16x8 kf1 = *reinterpret_cast<const bf16x8*>(kb + koffH[hx]);
      f32x4 acc = (f32x4){0.f, 0.f, 0.f, 0.f};
      acc = __builtin_amdgcn_mfma_f32_16x16x32_bf16(kf0, qf0, acc, 0, 0, 0);
      acc = __builtin_amdgcn_mfma_f32_16x16x32_bf16(kf1, qf1, acc, 0, 0, 0);
      float w[4];
      #pragma unroll
      for (int r = 0; r < 4; ++r) {
        const float knv = (r==0)?kn4[hx].x:(r==1)?kn4[hx].y:(r==2)?kn4[hx].z:kn4[hx].w;
        // u = SCALE * e^{-d2} = 2^{arg}   (bias -3 folded into knv)
        // no clamp: d2 >= ~30 for this data, arg << 0 always
        float arg = fmaf(TWO_LOG2E, acc[r], qnL + knv);
        float uu  = __builtin_amdgcn_exp2f(arg);
        // w' = e^{-u} ~= 1 - u + u^2/2   (err <= u^3/6 ~ 3.3e-4)
        float wv  = fmaf(uu, fmaf(0.5f, uu, -1.0f), 1.0f);
        if (MASK) {
          const int sof = 32*(hx>>1) + 8*lg + 4*(hx&1);
          wv = (s_base + sof + r <= l_glob) ? wv : 0.f;
        }
        den += wv;
        w[r] = wv;
      }
      up[hx][0] = pack_bf16(w[0], w[1]);
      up[hx][1] = pack_bf16(w[2], w[3]);
    }
    // ---- PV: P fragment lane-local by sigma construction ----
    #pragma unroll
    for (int sc = 0; sc < 2; ++sc) {
      union { unsigned u[4]; bf16x8 v; } pb;
      pb.u[0] = up[2*sc][0];
      pb.u[1] = up[2*sc][1];
      pb.u[2] = up[2*sc+1][0];
      pb.u[3] = up[2*sc+1][1];
      const bf16x8 pf = pb.v;
      #pragma unroll
      for (int dsb = 0; dsb < 4; ++dsb) {
        const bf16x8 vf = *reinterpret_cast<const bf16x8*>(vb + voff[sc][dsb]);
        oacc[dsb] = __builtin_amdgcn_mfma_f32_16x16x32_bf16(pf, vf, oacc[dsb], 0, 0, 0);
      }
    }
    __builtin_amdgcn_s_setprio(0);

    if (more) writeKV(B ^ 8192);
    __syncthreads();
  };

  {
    int i = 0;
    for (; i + 2 < n_it; i += 2) { body(i, 0, false); body(i + 1, 8192, false); }
    if ((n_it & 1) == 0) { body(n_it - 2, 0, false); body(n_it - 1, 8192, true); }
    else                 { body(n_it - 1, 0, true); }
  }

  // ---- den: reduce over lg (per l = lr) ----
  den += __shfl_xor(den, 16);
  den += __shfl_xor(den, 32);

  // ---- combine groups through LDS ----
  if (grp == 1) {
    #pragma unroll
    for (int dsb = 0; dsb < 4; ++dsb)
      #pragma unroll
      for (int r = 0; r < 4; ++r)
        Cbuf[(16*w4 + 4*lg + r) * 65 + 16*dsb + lr] = oacc[dsb][r];
    if (lane < 16) Dbuf[16*w4 + lr] = den;
  }
  __syncthreads();
  if (grp == 0) {
    const float dtot = den + Dbuf[16*w4 + lr];   // total den for l = 16*w4+lr
    float inv[4];
    #pragma unroll
    for (int r = 0; r < 4; ++r)
      inv[r] = 1.0f / __shfl(dtot, 4*lg + r);
    float* obase = Og + ((size_t)b * L + l0 + 16*w4) * 512 + h * 64;
    #pragma unroll
    for (int r = 0; r < 4; ++r) {
      float* orow = obase + (size_t)(4*lg + r) * 512;
      #pragma unroll
      for (int dsb = 0; dsb < 4; ++dsb) {
        const float s = oacc[dsb][r] + Cbuf[(16*w4 + 4*lg + r) * 65 + 16*dsb + lr];
        orow[16*dsb + lr] = s * inv[r];
      }
    }
  }
}

} // namespace

extern "C" void kernel_launch(void* const* d_in, const int* in_sizes, int n_in,
                              void* d_out, int out_size, void* d_ws, size_t ws_size,
                              hipStream_t stream) {
  (void)in_sizes; (void)n_in; (void)out_size; (void)ws_size;
  const float* q = (const float*)d_in[0];
  const float* k = (const float*)d_in[1];
  const float* v = (const float*)d_in[2];
  float*       o = (float*)d_out;

  char* ws = (char*)d_ws;
  float*  kn = (float*)(ws + KN_OFF);
  __bf16* Kb = (__bf16*)(ws + KB_OFF);
  __bf16* Vt = (__bf16*)(ws + VT_OFF);

  prep<<<dim3(1024), dim3(256), 0, stream>>>(k, v, Kb, kn, Vt);
  degr_attn<<<dim3(512), dim3(512), 0, stream>>>(q, Kb, Vt, kn, o);
}

// Round 19
// 38.210 us; speedup vs baseline: 1.1905x; 1.0197x over previous
//
#include <hip/hip_runtime.h>
#include <hip/hip_bf16.h>

typedef __attribute__((ext_vector_type(8))) __bf16 bf16x8;
typedef __attribute__((ext_vector_type(4))) float f32x4;

namespace {

constexpr int L = 2048;      // query length (== S)
constexpr int E = 64;        // embed dim == value dim
constexpr int NHEAD = 16;    // B*H reinterpreted heads
constexpr float LOG2E = 1.44269504f;
constexpr float TWO_LOG2E = 2.88539008f;

// workspace layout (bytes)
constexpr size_t KN_OFF = 4096;                               // f32 [16][2048]  (-log2e*|k|^2 - 3)
constexpr size_t KB_OFF = KN_OFF + (size_t)NHEAD * L * 4;     // bf16 [16][2048][64]
constexpr size_t VT_OFF = KB_OFF + (size_t)NHEAD * L * E * 2; // bf16 [16][64][2048]

// XOR swizzle within a 128-byte LDS row (verified low-conflict rounds 5-18)
__device__ __forceinline__ int swz(int row, int byte_in_row) {
  const int f = (row & 3) | (((row >> 3) & 1) << 2);
  return row * 128 + (byte_in_row ^ (f << 4));
}

__device__ __forceinline__ unsigned pack_bf16(float a, float b) {
  union { __bf16 h[2]; unsigned u; } p;
  p.h[0] = (__bf16)a; p.h[1] = (__bf16)b;
  return p.u;
}

__device__ __forceinline__ void cvt_row16(const float4* src, float& pn,
                                          bf16x8& w0, bf16x8& w1) {
  float4 a = src[0], c = src[1];
  pn += a.x*a.x + a.y*a.y + a.z*a.z + a.w*a.w;
  pn += c.x*c.x + c.y*c.y + c.z*c.z + c.w*c.w;
  w0[0]=(__bf16)a.x; w0[1]=(__bf16)a.y; w0[2]=(__bf16)a.z; w0[3]=(__bf16)a.w;
  w0[4]=(__bf16)c.x; w0[5]=(__bf16)c.y; w0[6]=(__bf16)c.z; w0[7]=(__bf16)c.w;
  float4 d = src[2], e = src[3];
  pn += d.x*d.x + d.y*d.y + d.z*d.z + d.w*d.w;
  pn += e.x*e.x + e.y*e.y + e.z*e.z + e.w*e.w;
  w1[0]=(__bf16)d.x; w1[1]=(__bf16)d.y; w1[2]=(__bf16)d.z; w1[3]=(__bf16)d.w;
  w1[4]=(__bf16)e.x; w1[5]=(__bf16)e.y; w1[6]=(__bf16)e.z; w1[7]=(__bf16)e.w;
}

// merged prep: blocks [0,512) convert K -> bf16 + biased scaled norms;
// [512,1024) transpose V.  kn stores (-log2e*|k|^2 - 3): the -3 folds the
// SCALE=2^-3 factor into the exp2 argument (u = SCALE*e^{-d2} = 2^{arg-3}).
__global__ __launch_bounds__(256)
void prep(const float* __restrict__ Kg, const float* __restrict__ Vg,
          __bf16* __restrict__ Kb, float* __restrict__ kn,
          __bf16* __restrict__ Vt) {
  __shared__ float Vs[64][65];
  const int t = threadIdx.x;
  if (blockIdx.x < 512) {
    const int row = blockIdx.x * 64 + (t >> 2);
    const int seg = t & 3;
    const float4* src = reinterpret_cast<const float4*>(
        Kg + (size_t)row * E + seg * 16);
    float pn = 0.f; bf16x8 w0, w1;
    cvt_row16(src, pn, w0, w1);
    __bf16* dst = Kb + (size_t)row * E + seg * 16;
    *reinterpret_cast<bf16x8*>(dst)     = w0;
    *reinterpret_cast<bf16x8*>(dst + 8) = w1;
    pn += __shfl_xor(pn, 1);
    pn += __shfl_xor(pn, 2);
    if (seg == 0) kn[row] = fmaf(-LOG2E, pn, -3.0f);   // pre-scaled + bias
  } else {
    const int bb = blockIdx.x - 512;
    const int n  = bb >> 5;    // head 0..15
    const int st = bb & 31;    // s-tile of 64
    const int b = n >> 3, h = n & 7;
    {
      const int srow = t >> 2, seg = t & 3;
      const float4* src = reinterpret_cast<const float4*>(
          Vg + ((size_t)b * L + st * 64 + srow) * 512 + h * 64 + seg * 16);
      #pragma unroll
      for (int jj = 0; jj < 4; ++jj) {
        float4 a = src[jj];
        Vs[srow][seg*16 + jj*4 + 0] = a.x;
        Vs[srow][seg*16 + jj*4 + 1] = a.y;
        Vs[srow][seg*16 + jj*4 + 2] = a.z;
        Vs[srow][seg*16 + jj*4 + 3] = a.w;
      }
    }
    __syncthreads();
    {
      const int d = t >> 2, sg = t & 3;
      bf16x8 o0, o1;
      #pragma unroll
      for (int i = 0; i < 8; ++i) o0[i] = (__bf16)Vs[sg*16 + i][d];
      #pragma unroll
      for (int i = 0; i < 8; ++i) o1[i] = (__bf16)Vs[sg*16 + 8 + i][d];
      __bf16* dst = Vt + (size_t)n * (E * L) + (size_t)d * L + st * 64 + sg * 16;
      *reinterpret_cast<bf16x8*>(dst)     = o0;
      *reinterpret_cast<bf16x8*>(dst + 8) = o1;
    }
  }
}

// ---- main attention: 8 waves = 2 groups (even/odd s-chunks), LDS combine ----
// Score path uses softmax constant-factor cancellation:
//   w' = w / e^SCALE = exp(-SCALE*e^{-d2}) ~= 1 - u + u^2/2,  u = 2^{arg-3}
// den computed via MFMA row-sum (B = ones): oden[r] = sum_k P[row][k],
// den for q-row 16w4+4lg+r lands directly in oden[r] on every lane.
__global__ __launch_bounds__(512, 4)
void degr_attn(const float* __restrict__ Qg, const __bf16* __restrict__ Kb,
               const __bf16* __restrict__ Vt, const float* __restrict__ kng,
               float* __restrict__ Og) {
  __shared__ char smem[65536];
  // per-group staging: K dbuf 16KB + V dbuf 16KB; overlay: Cbuf/Dbuf

  const int id = blockIdx.x;
  const int n  = (id & 7) | (((id >> 3) & 1) << 3);  // 2 heads per XCD
  const int u  = id >> 4;                            // 0..31
  const int lt = 31 - u;                             // LPT order (harmless)
  const int l0 = lt * 64;
  const int b = n >> 3, h = n & 7;

  const int t = threadIdx.x;
  const int wave = t >> 6, grp = wave >> 2, w4 = wave & 3;
  const int lane = t & 63, lg = lane >> 4, lr = lane & 15;
  const int gt = t & 255;   // group-local thread

  char* kbase = smem + grp * 32768;            // K: [2][8192] bytes
  char* vbase = smem + grp * 32768 + 16384;    // V: [2][8192] bytes
  float*  Cbuf = (float*)smem;                 // 64*65 f32 (overlay)
  float*  Dbuf = (float*)(smem + 17408);       // 64 f32

  const float*  Qh  = Qg  + (size_t)n * (L * E);
  const __bf16* Kh  = Kb  + (size_t)n * (L * E);
  const __bf16* Vh  = Vt  + (size_t)n * (E * L);
  const float*  knh = kng + (size_t)n * L;

  // ---- Q fragments direct from global (f32 -> bf16 in regs) + lane-local qn ----
  const int l_glob = l0 + 16 * w4 + lr;
  bf16x8 qf0, qf1;
  float qnL;
  {
    const float* qp = Qh + (size_t)l_glob * E + 8 * lg;
    float4 a = *reinterpret_cast<const float4*>(qp);
    float4 d = *reinterpret_cast<const float4*>(qp + 4);
    float4 a2 = *reinterpret_cast<const float4*>(qp + 32);
    float4 d2v = *reinterpret_cast<const float4*>(qp + 36);
    float pn = 0.f;
    #pragma unroll
    for (int i = 0; i < 4; ++i) {
      float v0 = (i==0)?a.x:(i==1)?a.y:(i==2)?a.z:a.w;
      float v1 = (i==0)?d.x:(i==1)?d.y:(i==2)?d.z:d.w;
      float v2 = (i==0)?a2.x:(i==1)?a2.y:(i==2)?a2.z:a2.w;
      float v3 = (i==0)?d2v.x:(i==1)?d2v.y:(i==2)?d2v.z:d2v.w;
      qf0[i]   = (__bf16)v0;  qf0[i+4] = (__bf16)v1;
      qf1[i]   = (__bf16)v2;  qf1[i+4] = (__bf16)v3;
      float f;
      f = (float)qf0[i];   pn += f*f;
      f = (float)qf0[i+4]; pn += f*f;
      f = (float)qf1[i];   pn += f*f;
      f = (float)qf1[i+4]; pn += f*f;
    }
    pn += __shfl_xor(pn, 16);
    pn += __shfl_xor(pn, 32);
    qnL = -LOG2E * pn;       // pre-scaled |q|^2 (bias lives in kn)
  }

  // ---- precomputed LDS offsets (all addressing hoisted out of the loop) ----
  const int srow = gt >> 2;
  const int scol = (gt & 3) * 2;
  const int wk0 = swz(srow, scol*16);
  const int wk1 = swz(srow, scol*16 + 16);
  int koffL[4], koffH[4];
  #pragma unroll
  for (int hx = 0; hx < 4; ++hx) {
    const int krow = 32*(hx>>1) + 8*(lr>>2) + 4*(hx&1) + (lr&3);
    koffL[hx] = swz(krow, lg*16);
    koffH[hx] = swz(krow, 64 + lg*16);
  }
  int voff[2][4];
  #pragma unroll
  for (int sc = 0; sc < 2; ++sc)
    #pragma unroll
    for (int dsb = 0; dsb < 4; ++dsb)
      voff[sc][dsb] = swz(dsb*16 + lr, sc*64 + lg*16);

  // all-ones bf16x8 B-operand for the den row-sum MFMA
  bf16x8 ones;
  #pragma unroll
  for (int i = 0; i < 8; ++i) ones[i] = (__bf16)1.0f;

  bf16x8 kr0, kr1, vr0, vr1;
  auto loadKV = [&](int c) {
    const int s0 = c * 64;
    const __bf16* kp = Kh + (size_t)(s0 + srow) * E + scol * 8;
    kr0 = *reinterpret_cast<const bf16x8*>(kp);
    kr1 = *reinterpret_cast<const bf16x8*>(kp + 8);
    const __bf16* vp = Vh + (size_t)srow * L + s0 + scol * 8;
    vr0 = *reinterpret_cast<const bf16x8*>(vp);
    vr1 = *reinterpret_cast<const bf16x8*>(vp + 8);
  };
  auto writeKV = [&](int WB) {       // WB: literal byte offset 0 / 8192
    *reinterpret_cast<bf16x8*>(kbase + WB + wk0) = kr0;
    *reinterpret_cast<bf16x8*>(kbase + WB + wk1) = kr1;
    *reinterpret_cast<bf16x8*>(vbase + WB + wk0) = vr0;
    *reinterpret_cast<bf16x8*>(vbase + WB + wk1) = vr1;
  };

  const int n_it = (lt >> 1) + 1;
  loadKV(grp <= lt ? grp : lt);
  writeKV(0);
  __syncthreads();

  f32x4 oacc[4];
  #pragma unroll
  for (int i = 0; i < 4; ++i) oacc[i] = (f32x4){0.f, 0.f, 0.f, 0.f};
  f32x4 oden = (f32x4){0.f, 0.f, 0.f, 0.f};

  auto body = [&](int i, const int B, const bool MASK) {
    const int c = 2 * i + grp;
    const bool more = (i + 1 < n_it);
    if (more) {
      int cn = 2 * (i + 1) + grp;
      loadKV(cn <= lt ? cn : lt);
    }
    const int s_base = c * 64;
    const char* kb = kbase + B;
    const char* vb = vbase + B;

    // prefetch kn for all 4 subtiles (consumed after QK^T)
    float4 kn4[4];
    kn4[0] = *reinterpret_cast<const float4*>(knh + s_base + 8*lg);
    kn4[1] = *reinterpret_cast<const float4*>(knh + s_base + 8*lg + 4);
    kn4[2] = *reinterpret_cast<const float4*>(knh + s_base + 32 + 8*lg);
    kn4[3] = *reinterpret_cast<const float4*>(knh + s_base + 36 + 8*lg);

    __builtin_amdgcn_s_setprio(1);
    unsigned up[4][2];
    #pragma unroll
    for (int hx = 0; hx < 4; ++hx) {
      const bf16x8 kf0 = *reinterpret_cast<const bf16x8*>(kb + koffL[hx]);
      const bf16x8 kf1 = *reinterpret_cast<const bf16x8*>(kb + koffH[hx]);
      f32x4 acc = (f32x4){0.f, 0.f, 0.f, 0.f};
      acc = __builtin_amdgcn_mfma_f32_16x16x32_bf16(kf0, qf0, acc, 0, 0, 0);
      acc = __builtin_amdgcn_mfma_f32_16x16x32_bf16(kf1, qf1, acc, 0, 0, 0);
      float w[4];
      #pragma unroll
      for (int r = 0; r < 4; ++r) {
        const float knv = (r==0)?kn4[hx].x:(r==1)?kn4[hx].y:(r==2)?kn4[hx].z:kn4[hx].w;
        // u = SCALE * e^{-d2} = 2^{arg}   (bias -3 folded into knv)
        float arg = fmaf(TWO_LOG2E, acc[r], qnL + knv);
        float uu  = __builtin_amdgcn_exp2f(arg);
        // w' = e^{-u} ~= 1 - u + u^2/2   (err <= u^3/6 ~ 3.3e-4)
        float wv  = fmaf(uu, fmaf(0.5f, uu, -1.0f), 1.0f);
        if (MASK) {
          const int sof = 32*(hx>>1) + 8*lg + 4*(hx&1);
          wv = (s_base + sof + r <= l_glob) ? wv : 0.f;
        }
        w[r] = wv;
      }
      up[hx][0] = pack_bf16(w[0], w[1]);
      up[hx][1] = pack_bf16(w[2], w[3]);
    }
    // ---- PV: P fragment lane-local by sigma construction; den via MFMA ----
    #pragma unroll
    for (int sc = 0; sc < 2; ++sc) {
      union { unsigned u[4]; bf16x8 v; } pb;
      pb.u[0] = up[2*sc][0];
      pb.u[1] = up[2*sc][1];
      pb.u[2] = up[2*sc+1][0];
      pb.u[3] = up[2*sc+1][1];
      const bf16x8 pf = pb.v;
      #pragma unroll
      for (int dsb = 0; dsb < 4; ++dsb) {
        const bf16x8 vf = *reinterpret_cast<const bf16x8*>(vb + voff[sc][dsb]);
        oacc[dsb] = __builtin_amdgcn_mfma_f32_16x16x32_bf16(pf, vf, oacc[dsb], 0, 0, 0);
      }
      oden = __builtin_amdgcn_mfma_f32_16x16x32_bf16(pf, ones, oden, 0, 0, 0);
    }
    __builtin_amdgcn_s_setprio(0);

    if (more) writeKV(B ^ 8192);
    __syncthreads();
  };

  {
    int i = 0;
    for (; i + 2 < n_it; i += 2) { body(i, 0, false); body(i + 1, 8192, false); }
    if ((n_it & 1) == 0) { body(n_it - 2, 0, false); body(n_it - 1, 8192, true); }
    else                 { body(n_it - 1, 0, true); }
  }

  // oden[r] = den for q-row l0 + 16*w4 + 4*lg + r (replicated across lr)

  // ---- combine groups through LDS ----
  if (grp == 1) {
    #pragma unroll
    for (int dsb = 0; dsb < 4; ++dsb)
      #pragma unroll
      for (int r = 0; r < 4; ++r)
        Cbuf[(16*w4 + 4*lg + r) * 65 + 16*dsb + lr] = oacc[dsb][r];
    if (lr == 0) {
      #pragma unroll
      for (int r = 0; r < 4; ++r)
        Dbuf[16*w4 + 4*lg + r] = oden[r];
    }
  }
  __syncthreads();
  if (grp == 0) {
    float inv[4];
    #pragma unroll
    for (int r = 0; r < 4; ++r)
      inv[r] = 1.0f / (oden[r] + Dbuf[16*w4 + 4*lg + r]);
    float* obase = Og + ((size_t)b * L + l0 + 16*w4) * 512 + h * 64;
    #pragma unroll
    for (int r = 0; r < 4; ++r) {
      float* orow = obase + (size_t)(4*lg + r) * 512;
      #pragma unroll
      for (int dsb = 0; dsb < 4; ++dsb) {
        const float s = oacc[dsb][r] + Cbuf[(16*w4 + 4*lg + r) * 65 + 16*dsb + lr];
        orow[16*dsb + lr] = s * inv[r];
      }
    }
  }
}

} // namespace

extern "C" void kernel_launch(void* const* d_in, const int* in_sizes, int n_in,
                              void* d_out, int out_size, void* d_ws, size_t ws_size,
                              hipStream_t stream) {
  (void)in_sizes; (void)n_in; (void)out_size; (void)ws_size;
  const float* q = (const float*)d_in[0];
  const float* k = (const float*)d_in[1];
  const float* v = (const float*)d_in[2];
  float*       o = (float*)d_out;

  char* ws = (char*)d_ws;
  float*  kn = (float*)(ws + KN_OFF);
  __bf16* Kb = (__bf16*)(ws + KB_OFF);
  __bf16* Vt = (__bf16*)(ws + VT_OFF);

  prep<<<dim3(1024), dim3(256), 0, stream>>>(k, v, Kb, kn, Vt);
  degr_attn<<<dim3(512), dim3(512), 0, stream>>>(q, Kb, Vt, kn, o);
}